// Round 13
// baseline (1179.343 us; speedup 1.0000x reference)
//
#include <hip/hip_runtime.h>
#include <hip/hip_bf16.h>

#define B_ 256
#define T_ 512
#define I_ 128
#define H_ 256

// 2*log2(e): W_ih, W_hh, bias pre-scaled so the accumulator holds
// s = 2*log2e*z and tanh(z) = 1 - 2/(1 + 2^s) needs no pre-multiply.
// ALL transcendentals via compiler builtins — inline-asm v_exp_f32 was the
// pinned corruption mechanism in EVERY failed round (R2-R6): the TRANS-op
// hazard recognizer cannot see inside asm strings. Every builtin-only
// kernel (R9/R10/R11/R12, incl. two novel structures) passed correctness.
#define SC 2.885390081777927f

typedef __bf16 bf16x8 __attribute__((ext_vector_type(8)));
typedef float  f32x4  __attribute__((ext_vector_type(4)));
typedef unsigned short u16;
typedef unsigned int   u32;

union U16x8Cast { uint4 v; bf16x8 b; };

__device__ inline u16 f2b(float f) {           // fp32 -> bf16 bits (RNE)
    union { __bf16 h; u16 u; } c; c.h = (__bf16)f; return c.u;
}
__device__ inline bf16x8 pack8(float4 lo, float4 hi) {
    bf16x8 f;
    f[0]=(__bf16)lo.x; f[1]=(__bf16)lo.y; f[2]=(__bf16)lo.z; f[3]=(__bf16)lo.w;
    f[4]=(__bf16)hi.x; f[5]=(__bf16)hi.y; f[6]=(__bf16)hi.z; f[7]=(__bf16)hi.w;
    return f;
}
__device__ inline bf16x8 pack8s(float4 lo, float4 hi, float s) {
    bf16x8 f;
    f[0]=(__bf16)(lo.x*s); f[1]=(__bf16)(lo.y*s); f[2]=(__bf16)(lo.z*s); f[3]=(__bf16)(lo.w*s);
    f[4]=(__bf16)(hi.x*s); f[5]=(__bf16)(hi.y*s); f[6]=(__bf16)(hi.z*s); f[7]=(__bf16)(hi.w*s);
    return f;
}
__device__ inline uint2 pack4(float a, float b, float c, float d) {
    uint2 p;
    p.x = (u32)f2b(a) | ((u32)f2b(b) << 16);
    p.y = (u32)f2b(c) | ((u32)f2b(d) << 16);
    return p;
}
// tanh from pre-scaled s = 2*log2e*z: tanh(z) = 1 - 2/(1 + 2^s).
// Builtins only (R9-verified). s->+inf: 1; s->-inf: -1. No NaN.
__device__ inline float tanh_pre(float s) {
    float e = __builtin_amdgcn_exp2f(s);
    float r = __builtin_amdgcn_rcpf(1.f + e);
    return fmaf(-2.f, r, 1.f);
}

// LDS-drain-only workgroup barrier: does NOT wait vmcnt, so the global
// x-prefetch loads stay in flight across the barrier. (verified R0/R9)
#define WG_BARRIER() asm volatile("s_waitcnt lgkmcnt(0)\n\ts_barrier" ::: "memory")

// =====================================================================
// FUSED kernel: input GEMM (x @ W_ih^T + bias) computed inline per scan
// step — deletes kernel 1 (~55us) and the 134 MB xw round-trip.
//
// Structure = the R9-verified 8-wave barrier scan with, per step:
//  1. 8 hoisted ds_read_b128 (h B-frags) issued FIRST -> port drains early
//  2. port-independent work fills the drain window: x-frag cvt-packs,
//     fp32 bias acc init, x prefetch reissue (depth 1: a full step
//     ~1480cyc >> HBM latency), 8 input-GEMM MFMAs on W_ih frags
//  3. recurrent MFMAs as h reads land (compiler-placed lgkmcnt)
//  4. builtin tanh -> bf16 h-write -> WG_BARRIER (lgkm-only)
// MFMA total identical to the two-kernel version; the GEMM FLOPs moved
// into pipes that R9's counters show idle during the port drain.
// R4's prior failure of this exact dataflow is fully attributed to its
// asm-v_exp (bounded-tanh output made absmax=97 impossible from dataflow;
// R12 proved the protocol-side suspicion wrong by passing).
// x loads: all 8 waves read the same 8 KB/step tile -> L1 broadcast;
// HBM reads x exactly once (67 MB total).
// =====================================================================
__global__ __launch_bounds__(512, 1) void rnn_fused(const float* __restrict__ x,
                                                    const float* __restrict__ W_ih,
                                                    const float* __restrict__ W_hh,
                                                    const float* __restrict__ b_ih,
                                                    const float* __restrict__ b_hh,
                                                    const float* __restrict__ fc_w,
                                                    const float* __restrict__ fc_b,
                                                    float* __restrict__ out) {
    __shared__ __attribute__((aligned(16))) u16 hbuf[2][4096];  // 2 x 8 KB
    __shared__ float red[8][16];

    const int tid  = (int)threadIdx.x;
    const int wave = tid >> 6;          // 0..7, owns n-rows [wave*32, wave*32+32)
    const int lane = tid & 63;
    const int q    = lane >> 4;
    const int m    = lane & 15;
    const int b0   = (int)blockIdx.x * 16;

    // W_hh A-frags (SC-scaled): lane holds SC*W_hh[wave*32+tau2*16+m][kap*32+q*8+0..7]
    bf16x8 wf[2][8];
#pragma unroll
    for (int tau2 = 0; tau2 < 2; ++tau2) {
        const float* wr = W_hh + (size_t)(wave * 32 + tau2 * 16 + m) * H_;
#pragma unroll
        for (int kap = 0; kap < 8; ++kap) {
            const int k0 = kap * 32 + q * 8;
            wf[tau2][kap] = pack8s(*(const float4*)(wr + k0), *(const float4*)(wr + k0 + 4), SC);
        }
    }
    // W_ih A-frags (SC-scaled): same n-rows, k over I=128 (4 kap chunks)
    bf16x8 wi[2][4];
#pragma unroll
    for (int tau2 = 0; tau2 < 2; ++tau2) {
        const float* wr = W_ih + (size_t)(wave * 32 + tau2 * 16 + m) * I_;
#pragma unroll
        for (int kap = 0; kap < 4; ++kap) {
            const int k0 = kap * 32 + q * 8;
            wi[tau2][kap] = pack8s(*(const float4*)(wr + k0), *(const float4*)(wr + k0 + 4), SC);
        }
    }

    // fp32 bias accumulator init: acc[tau2][j] covers n = wave*32+tau2*16+q*4+j
    f32x4 bias2[2];
#pragma unroll
    for (int tau2 = 0; tau2 < 2; ++tau2) {
        const int n = wave * 32 + tau2 * 16 + q * 4;
        float4 bi = *(const float4*)(b_ih + n);
        float4 bh = *(const float4*)(b_hh + n);
        bias2[tau2][0] = (bi.x + bh.x) * SC;
        bias2[tau2][1] = (bi.y + bh.y) * SC;
        bias2[tau2][2] = (bi.z + bh.z) * SC;
        bias2[tau2][3] = (bi.w + bh.w) * SC;
    }

    // LDS write indices (u16 units) for C -> B-frag relayout
    int widx[2];
#pragma unroll
    for (int tau2 = 0; tau2 < 2; ++tau2) {
        const int nbw = wave * 32 + tau2 * 16 + q * 4;
        widx[tau2] = (nbw >> 5) * 512 + (((nbw >> 3) & 3) * 16 + m) * 8 + (nbw & 7);
    }

    {   // zero h buffer 0 (8 KB = 512 uint4, 512 threads)
        uint4* p = (uint4*)&hbuf[0][0];
        const uint4 z = {0u, 0u, 0u, 0u};
        p[tid] = z;
    }
    __syncthreads();

    // x B-frag prefetch: lane (q,m) holds x[b0+m][t][kap*32+q*8 + 0..7] (f32).
    const float* xrow = x + ((size_t)(b0 + m) * T_) * I_ + q * 8;
    float4 xpf[8];
#pragma unroll
    for (int kap = 0; kap < 4; ++kap) {
        xpf[2 * kap]     = *(const float4*)(xrow + kap * 32);
        xpf[2 * kap + 1] = *(const float4*)(xrow + kap * 32 + 4);
    }

    int cur = 0;
    f32x4 acc[2];
    for (int t = 0; t < T_; ++t) {
        // 1. hoisted h B-frag reads — issue FIRST so the port drains early
        const uint4* hb = (const uint4*)&hbuf[cur][0];
        U16x8Cast cv[8];
#pragma unroll
        for (int kap = 0; kap < 8; ++kap) cv[kap].v = hb[kap * 64 + lane];

        // 2. port-independent work fills the drain window
        bf16x8 xB[4];
#pragma unroll
        for (int kap = 0; kap < 4; ++kap) xB[kap] = pack8(xpf[2 * kap], xpf[2 * kap + 1]);
        acc[0] = bias2[0];
        acc[1] = bias2[1];
        if (t + 1 < T_) {
            const float* xp = xrow + (size_t)(t + 1) * I_;
#pragma unroll
            for (int kap = 0; kap < 4; ++kap) {
                xpf[2 * kap]     = *(const float4*)(xp + kap * 32);
                xpf[2 * kap + 1] = *(const float4*)(xp + kap * 32 + 4);
            }
        }
#pragma unroll
        for (int kap = 0; kap < 4; ++kap) {
            acc[0] = __builtin_amdgcn_mfma_f32_16x16x32_bf16(wi[0][kap], xB[kap], acc[0], 0, 0, 0);
            acc[1] = __builtin_amdgcn_mfma_f32_16x16x32_bf16(wi[1][kap], xB[kap], acc[1], 0, 0, 0);
        }

        // 3. recurrent MFMAs as the h reads land
#pragma unroll
        for (int kap = 0; kap < 8; ++kap) {
            acc[0] = __builtin_amdgcn_mfma_f32_16x16x32_bf16(wf[0][kap], cv[kap].b, acc[0], 0, 0, 0);
            acc[1] = __builtin_amdgcn_mfma_f32_16x16x32_bf16(wf[1][kap], cv[kap].b, acc[1], 0, 0, 0);
        }

        // 4. tanh -> bf16 h-write -> barrier (last h feeds fc only)
        if (t != T_ - 1) {
            u16* wb = &hbuf[cur ^ 1][0];
#pragma unroll
            for (int tau2 = 0; tau2 < 2; ++tau2) {
                uint2 pk = pack4(tanh_pre(acc[tau2][0]), tanh_pre(acc[tau2][1]),
                                 tanh_pre(acc[tau2][2]), tanh_pre(acc[tau2][3]));
                *(uint2*)(wb + widx[tau2]) = pk;
            }
            WG_BARRIER();
            cur ^= 1;
        }
    }

    // fc head: out[b] = sum_n tanh(h)[n] * fc_w[n] + fc_b
    float4 fcw[2];
#pragma unroll
    for (int tau2 = 0; tau2 < 2; ++tau2)
        fcw[tau2] = *(const float4*)(fc_w + wave * 32 + tau2 * 16 + q * 4);

    float partial = 0.f;
#pragma unroll
    for (int tau2 = 0; tau2 < 2; ++tau2) {
        partial += tanh_pre(acc[tau2][0]) * fcw[tau2].x;
        partial += tanh_pre(acc[tau2][1]) * fcw[tau2].y;
        partial += tanh_pre(acc[tau2][2]) * fcw[tau2].z;
        partial += tanh_pre(acc[tau2][3]) * fcw[tau2].w;
    }
    partial += __shfl_xor(partial, 16);
    partial += __shfl_xor(partial, 32);
    __syncthreads();
    if (lane < 16) red[wave][m] = partial;
    __syncthreads();
    if (tid < 16) {
        float s = red[0][tid] + red[1][tid] + red[2][tid] + red[3][tid]
                + red[4][tid] + red[5][tid] + red[6][tid] + red[7][tid];
        out[b0 + tid] = s + fc_b[0];
    }
}

// =====================================================================
extern "C" void kernel_launch(void* const* d_in, const int* in_sizes, int n_in,
                              void* d_out, int out_size, void* d_ws, size_t ws_size,
                              hipStream_t stream) {
    const float* x    = (const float*)d_in[0];
    const float* W_ih = (const float*)d_in[1];
    const float* W_hh = (const float*)d_in[2];
    const float* b_ih = (const float*)d_in[3];
    const float* b_hh = (const float*)d_in[4];
    const float* fc_w = (const float*)d_in[5];
    const float* fc_b = (const float*)d_in[6];
    float* out = (float*)d_out;

    rnn_fused<<<B_ / 16, 512, 0, stream>>>(x, W_ih, W_hh, b_ih, b_hh, fc_w, fc_b, out);
}

// Round 14
// 370.059 us; speedup vs baseline: 3.1869x; 3.1869x over previous
//
#include <hip/hip_runtime.h>
#include <hip/hip_bf16.h>

#define B_ 256
#define T_ 512
#define I_ 128
#define H_ 256

// 2*log2(e): W_ih, W_hh, bias pre-scaled so the scan accumulator holds
// s = 2*log2e*z and tanh(z) = 1 - 2/(1 + 2^s) needs no pre-multiply.
// ALL transcendentals via compiler builtins — inline-asm v_exp_f32 was the
// pinned corruption mechanism in EVERY failed round (R2-R6): the TRANS-op
// hazard recognizer cannot see inside asm strings.
#define SC 2.885390081777927f

typedef __bf16 bf16x8 __attribute__((ext_vector_type(8)));
typedef float  f32x4  __attribute__((ext_vector_type(4)));
typedef unsigned short u16;
typedef unsigned int   u32;

union U16x8Cast { uint4 v; bf16x8 b; };

__device__ inline u16 f2b(float f) {           // fp32 -> bf16 bits (RNE)
    union { __bf16 h; u16 u; } c; c.h = (__bf16)f; return c.u;
}
__device__ inline bf16x8 pack8(float4 lo, float4 hi) {
    bf16x8 f;
    f[0]=(__bf16)lo.x; f[1]=(__bf16)lo.y; f[2]=(__bf16)lo.z; f[3]=(__bf16)lo.w;
    f[4]=(__bf16)hi.x; f[5]=(__bf16)hi.y; f[6]=(__bf16)hi.z; f[7]=(__bf16)hi.w;
    return f;
}
__device__ inline bf16x8 pack8s(float4 lo, float4 hi, float s) {
    bf16x8 f;
    f[0]=(__bf16)(lo.x*s); f[1]=(__bf16)(lo.y*s); f[2]=(__bf16)(lo.z*s); f[3]=(__bf16)(lo.w*s);
    f[4]=(__bf16)(hi.x*s); f[5]=(__bf16)(hi.y*s); f[6]=(__bf16)(hi.z*s); f[7]=(__bf16)(hi.w*s);
    return f;
}
__device__ inline uint2 pack4(float a, float b, float c, float d) {
    uint2 p;
    p.x = (u32)f2b(a) | ((u32)f2b(b) << 16);
    p.y = (u32)f2b(c) | ((u32)f2b(d) << 16);
    return p;
}
__device__ inline f32x4 b4_to_f32x4(uint2 u) {
    f32x4 r;
    r[0] = __uint_as_float(u.x << 16);
    r[1] = __uint_as_float(u.x & 0xFFFF0000u);
    r[2] = __uint_as_float(u.y << 16);
    r[3] = __uint_as_float(u.y & 0xFFFF0000u);
    return r;
}
// tanh from pre-scaled s = 2*log2e*z: tanh(z) = 1 - 2/(1 + 2^s).
// Builtins only (R9-verified). s->+inf: 1; s->-inf: -1. No NaN.
__device__ inline float tanh_pre(float s) {
    float e = __builtin_amdgcn_exp2f(s);
    float r = __builtin_amdgcn_rcpf(1.f + e);
    return fmaf(-2.f, r, 1.f);
}

// LDS-drain-only workgroup barrier: does NOT wait vmcnt, so global
// prefetch loads stay in flight across the barrier. (verified R0/R9)
#define WG_BARRIER() asm volatile("s_waitcnt lgkmcnt(0)\n\ts_barrier" ::: "memory")

// =====================================================================
// Kernel 1 (MFMA GEMM): xw[t][b][n] = SC * (x[bT+t,:]*W_ih[n,:] + bias)
// VERBATIM the R1/R9 128-row version. The [t][b][n] materialization is
// load-bearing: it gives the GEMM coalesced row-major x access and the
// scan coalesced [b][n] reads; R13 measured the fused alternative
// (batch-strided x reads, 256KB stride -> L1 set aliasing) at 4.3x worse.
// =====================================================================
#define LDST 264
__global__ __launch_bounds__(256, 2) void xw_gemm_mfma(const float* __restrict__ x,
                                                       const float* __restrict__ W_ih,
                                                       const float* __restrict__ b_ih,
                                                       const float* __restrict__ b_hh,
                                                       u16* __restrict__ xw) {
    __shared__ u16 tile[64 * LDST];

    const int tid  = (int)threadIdx.x;
    const int wave = tid >> 6;
    const int lane = tid & 63;
    const int q    = lane >> 4;
    const int ml   = lane & 15;
    const int m0   = (int)blockIdx.x * 128;
    const int b    = m0 >> 9;
    const int t0   = m0 & 511;
    const int n0   = wave * 64;

    bf16x8 wA[4][4];
#pragma unroll
    for (int tau = 0; tau < 4; ++tau) {
        const float* wr = W_ih + (size_t)(n0 + tau * 16 + ml) * I_;
#pragma unroll
        for (int kap = 0; kap < 4; ++kap) {
            const int k0 = kap * 32 + q * 8;
            wA[tau][kap] = pack8s(*(const float4*)(wr + k0), *(const float4*)(wr + k0 + 4), SC);
        }
    }

    f32x4 acc[8][4];
#pragma unroll
    for (int mt = 0; mt < 8; ++mt)
#pragma unroll
        for (int tau = 0; tau < 4; ++tau) acc[mt][tau] = (f32x4)0.f;

#pragma unroll
    for (int kap = 0; kap < 4; ++kap) {
        bf16x8 xB[8];
#pragma unroll
        for (int mt = 0; mt < 8; ++mt) {
            const float* xr = x + (size_t)(m0 + mt * 16 + ml) * I_ + kap * 32 + q * 8;
            xB[mt] = pack8(*(const float4*)xr, *(const float4*)(xr + 4));
        }
#pragma unroll
        for (int mt = 0; mt < 8; ++mt)
#pragma unroll
            for (int tau = 0; tau < 4; ++tau)
                acc[mt][tau] = __builtin_amdgcn_mfma_f32_16x16x32_bf16(
                    wA[tau][kap], xB[mt], acc[mt][tau], 0, 0, 0);
    }

    float4 bias4[4];
#pragma unroll
    for (int tau = 0; tau < 4; ++tau) {
        const int n = n0 + tau * 16 + q * 4;
        float4 bi = *(const float4*)(b_ih + n);
        float4 bh = *(const float4*)(b_hh + n);
        bias4[tau] = make_float4((bi.x + bh.x) * SC, (bi.y + bh.y) * SC,
                                 (bi.z + bh.z) * SC, (bi.w + bh.w) * SC);
    }

#pragma unroll
    for (int p = 0; p < 2; ++p) {
        if (p) __syncthreads();
#pragma unroll
        for (int mt = 0; mt < 4; ++mt) {
            const int row = mt * 16 + ml;
            const int mg  = p * 4 + mt;
#pragma unroll
            for (int tau = 0; tau < 4; ++tau) {
                uint2 pk = pack4(acc[mg][tau][0] + bias4[tau].x,
                                 acc[mg][tau][1] + bias4[tau].y,
                                 acc[mg][tau][2] + bias4[tau].z,
                                 acc[mg][tau][3] + bias4[tau].w);
                *(uint2*)(tile + row * LDST + n0 + tau * 16 + q * 4) = pk;
            }
        }
        __syncthreads();
#pragma unroll
        for (int s = 0; s < 4; ++s) {
            const int rr = s * 16 + (tid >> 4);
            const int c  = tid & 15;
            const uint4* srcp = (const uint4*)(tile + rr * LDST);
            uint4* dstp = (uint4*)(xw + ((size_t)(t0 + p * 64 + rr) * B_ + b) * H_);
            uint4 v0 = srcp[c];
            uint4 v1 = srcp[c + 16];
            dstp[c] = v0;
            dstp[c + 16] = v1;
        }
    }
}

// =====================================================================
// Kernel 2 (MFMA scan) — the verified optimum (R9, 315us):
// 8 waves / launch_bounds(512,2) / double-buffered h / uniform WG_BARRIER
// / pfA-pfB alternating prefetch / SC-prescaled wf / builtin tanh_pre.
// Every structural alternative measured worse: 4 waves +27% (R1), flag
// de-phasing +42% (R12: acquire's wave-wide lgkmcnt(0) drains h reads),
// dual-group +73% wall (R10: CU halving), fusion +330% (R13: x-stride
// L1 aliasing). Step = port drain (~770cyc, 64 ds_read_b128) + tanh tail
// + barrier = 1480cyc; wall = T x step is forced by the recurrence.
// =====================================================================
__global__ __launch_bounds__(512, 2) void rnn_scan_mfma(const u16* __restrict__ xw,
                                                        const float* __restrict__ W_hh,
                                                        const float* __restrict__ fc_w,
                                                        const float* __restrict__ fc_b,
                                                        float* __restrict__ out) {
    __shared__ __attribute__((aligned(16))) u16 hbuf[2][4096];  // 2 x 8 KB
    __shared__ float red[8][16];

    const int tid  = (int)threadIdx.x;
    const int wave = tid >> 6;          // 0..7
    const int lane = tid & 63;
    const int q    = lane >> 4;
    const int m    = lane & 15;
    const int b0   = (int)blockIdx.x * 16;

    // W_hh A-frags (SC-scaled): lane holds SC*W_hh[wave*32+tau2*16+m][kap*32+q*8+0..7]
    bf16x8 wf[2][8];
#pragma unroll
    for (int tau2 = 0; tau2 < 2; ++tau2) {
        const float* wr = W_hh + (size_t)(wave * 32 + tau2 * 16 + m) * H_;
#pragma unroll
        for (int kap = 0; kap < 8; ++kap) {
            const int k0 = kap * 32 + q * 8;
            wf[tau2][kap] = pack8s(*(const float4*)(wr + k0), *(const float4*)(wr + k0 + 4), SC);
        }
    }

    // LDS write indices (u16 units) for C -> B-frag relayout
    int widx[2];
#pragma unroll
    for (int tau2 = 0; tau2 < 2; ++tau2) {
        const int nbw = wave * 32 + tau2 * 16 + q * 4;
        widx[tau2] = (nbw >> 5) * 512 + (((nbw >> 3) & 3) * 16 + m) * 8 + (nbw & 7);
    }

    {   // zero h buffer 0 (8 KB = 512 uint4)
        uint4* p = (uint4*)&hbuf[0][0];
        const uint4 z = {0u, 0u, 0u, 0u};
        p[tid] = z;
    }
    WG_BARRIER();

    // xw ([t][b][n]): lane reads 2 x uint2 per step.
    const u16* xwp = xw + (size_t)(b0 + m) * H_ + (wave * 32 + q * 4);
    const size_t tstride = (size_t)B_ * H_;

    uint2 pfA[2], pfB[2];                              // alternating, never copied
    pfA[0] = *(const uint2*)(xwp);
    pfA[1] = *(const uint2*)(xwp + 16);
    pfB[0] = *(const uint2*)(xwp + tstride);
    pfB[1] = *(const uint2*)(xwp + tstride + 16);

    int cur = 0;
    f32x4 acc[2];
    for (int tt = 0; tt < T_ / 2; ++tt) {
        // ---------- step A: t = 2*tt (even, never last) ----------
        {
            const int t = 2 * tt;
            acc[0] = b4_to_f32x4(pfA[0]);
            acc[1] = b4_to_f32x4(pfA[1]);
            if (t + 2 < T_) {                          // reload pfA for t+2
                const u16* pt = xwp + (size_t)(t + 2) * tstride;
                pfA[0] = *(const uint2*)(pt);
                pfA[1] = *(const uint2*)(pt + 16);
            }
            const uint4* hb = (const uint4*)&hbuf[cur][0];
#pragma unroll
            for (int kap = 0; kap < 8; ++kap) {
                U16x8Cast c; c.v = hb[kap * 64 + lane];
                acc[0] = __builtin_amdgcn_mfma_f32_16x16x32_bf16(wf[0][kap], c.b, acc[0], 0, 0, 0);
                acc[1] = __builtin_amdgcn_mfma_f32_16x16x32_bf16(wf[1][kap], c.b, acc[1], 0, 0, 0);
            }
            u16* wb = &hbuf[cur ^ 1][0];
#pragma unroll
            for (int tau2 = 0; tau2 < 2; ++tau2) {
                uint2 pk = pack4(tanh_pre(acc[tau2][0]), tanh_pre(acc[tau2][1]),
                                 tanh_pre(acc[tau2][2]), tanh_pre(acc[tau2][3]));
                *(uint2*)(wb + widx[tau2]) = pk;
            }
            WG_BARRIER();
            cur ^= 1;
        }
        // ---------- step B: t = 2*tt+1 (t = T_-1 on the last iter) ----------
        {
            const int t = 2 * tt + 1;
            acc[0] = b4_to_f32x4(pfB[0]);
            acc[1] = b4_to_f32x4(pfB[1]);
            if (t + 2 < T_) {                          // reload pfB for t+2
                const u16* pt = xwp + (size_t)(t + 2) * tstride;
                pfB[0] = *(const uint2*)(pt);
                pfB[1] = *(const uint2*)(pt + 16);
            }
            const uint4* hb = (const uint4*)&hbuf[cur][0];
#pragma unroll
            for (int kap = 0; kap < 8; ++kap) {
                U16x8Cast c; c.v = hb[kap * 64 + lane];
                acc[0] = __builtin_amdgcn_mfma_f32_16x16x32_bf16(wf[0][kap], c.b, acc[0], 0, 0, 0);
                acc[1] = __builtin_amdgcn_mfma_f32_16x16x32_bf16(wf[1][kap], c.b, acc[1], 0, 0, 0);
            }
            if (t != T_ - 1) {                         // last h feeds fc only
                u16* wb = &hbuf[cur ^ 1][0];
#pragma unroll
                for (int tau2 = 0; tau2 < 2; ++tau2) {
                    uint2 pk = pack4(tanh_pre(acc[tau2][0]), tanh_pre(acc[tau2][1]),
                                     tanh_pre(acc[tau2][2]), tanh_pre(acc[tau2][3]));
                    *(uint2*)(wb + widx[tau2]) = pk;
                }
                WG_BARRIER();
                cur ^= 1;
            }
        }
    }

    // fc head: out[b] = sum_n tanh(h)[n] * fc_w[n] + fc_b
    float4 fcw[2];
#pragma unroll
    for (int tau2 = 0; tau2 < 2; ++tau2)
        fcw[tau2] = *(const float4*)(fc_w + wave * 32 + tau2 * 16 + q * 4);

    float partial = 0.f;
#pragma unroll
    for (int tau2 = 0; tau2 < 2; ++tau2) {
        partial += tanh_pre(acc[tau2][0]) * fcw[tau2].x;
        partial += tanh_pre(acc[tau2][1]) * fcw[tau2].y;
        partial += tanh_pre(acc[tau2][2]) * fcw[tau2].z;
        partial += tanh_pre(acc[tau2][3]) * fcw[tau2].w;
    }
    partial += __shfl_xor(partial, 16);
    partial += __shfl_xor(partial, 32);
    __syncthreads();
    if (lane < 16) red[wave][m] = partial;
    __syncthreads();
    if (tid < 16) {
        float s = red[0][tid] + red[1][tid] + red[2][tid] + red[3][tid]
                + red[4][tid] + red[5][tid] + red[6][tid] + red[7][tid];
        out[b0 + tid] = s + fc_b[0];
    }
}

// =====================================================================
extern "C" void kernel_launch(void* const* d_in, const int* in_sizes, int n_in,
                              void* d_out, int out_size, void* d_ws, size_t ws_size,
                              hipStream_t stream) {
    const float* x    = (const float*)d_in[0];
    const float* W_ih = (const float*)d_in[1];
    const float* W_hh = (const float*)d_in[2];
    const float* b_ih = (const float*)d_in[3];
    const float* b_hh = (const float*)d_in[4];
    const float* fc_w = (const float*)d_in[5];
    const float* fc_b = (const float*)d_in[6];
    float* out = (float*)d_out;

    u16* xwbuf = (u16*)d_ws;                           // 64 MB bf16 [T][B][H]
    xw_gemm_mfma<<<(B_ * T_) / 128, 256, 0, stream>>>(x, W_ih, b_ih, b_hh, xwbuf);
    rnn_scan_mfma<<<B_ / 16, 512, 0, stream>>>(xwbuf, W_hh, fc_w, fc_b, out);
}